// Round 1
// baseline (417.297 us; speedup 1.0000x reference)
//
#include <hip/hip_runtime.h>
#include <math.h>

#define NBATCH 512
#define TLEN   2048
#define NS     24
#define KSTART 22
#define KSTOP  23
#define MID    1024
#define L2E    1.4426950408889634f
#define LN2F   0.6931471805599453f
#define NEGBIG (-1e30f)

__device__ __forceinline__ float fexp2(float x) {
#if __has_builtin(__builtin_amdgcn_exp2f)
  return __builtin_amdgcn_exp2f(x);
#else
  return exp2f(x);
#endif
}
__device__ __forceinline__ float flog2(float x) {
#if __has_builtin(__builtin_amdgcn_logf)
  return __builtin_amdgcn_logf(x);
#else
  return __log2f(x);
#endif
}

// broadcast lane J's value within each 32-lane group (BitMode: and=0,or=J,xor=0)
#define SWZ(X, IMM) __int_as_float(__builtin_amdgcn_ds_swizzle(__float_as_int(X), (IMM)))

#define DOTALL(G) \
  y0 = fmaf(p[0],  SWZ(G, (0<<5)),  y0); \
  y1 = fmaf(p[1],  SWZ(G, (1<<5)),  y1); \
  y2 = fmaf(p[2],  SWZ(G, (2<<5)),  y2); \
  y3 = fmaf(p[3],  SWZ(G, (3<<5)),  y3); \
  y0 = fmaf(p[4],  SWZ(G, (4<<5)),  y0); \
  y1 = fmaf(p[5],  SWZ(G, (5<<5)),  y1); \
  y2 = fmaf(p[6],  SWZ(G, (6<<5)),  y2); \
  y3 = fmaf(p[7],  SWZ(G, (7<<5)),  y3); \
  y0 = fmaf(p[8],  SWZ(G, (8<<5)),  y0); \
  y1 = fmaf(p[9],  SWZ(G, (9<<5)),  y1); \
  y2 = fmaf(p[10], SWZ(G, (10<<5)), y2); \
  y3 = fmaf(p[11], SWZ(G, (11<<5)), y3); \
  y0 = fmaf(p[12], SWZ(G, (12<<5)), y0); \
  y1 = fmaf(p[13], SWZ(G, (13<<5)), y1); \
  y2 = fmaf(p[14], SWZ(G, (14<<5)), y2); \
  y3 = fmaf(p[15], SWZ(G, (15<<5)), y3); \
  y0 = fmaf(p[16], SWZ(G, (16<<5)), y0); \
  y1 = fmaf(p[17], SWZ(G, (17<<5)), y1); \
  y2 = fmaf(p[18], SWZ(G, (18<<5)), y2); \
  y3 = fmaf(p[19], SWZ(G, (19<<5)), y3); \
  y0 = fmaf(p[20], SWZ(G, (20<<5)), y0); \
  y1 = fmaf(p[21], SWZ(G, (21<<5)), y1); \
  y2 = fmaf(p[22], SWZ(G, (22<<5)), y2); \
  y3 = fmaf(p[23], SWZ(G, (23<<5)), y3);

// one wave per batch: lanes 0..23 = forward chain states, lanes 32..55 = backward chain states.
// Log-domain recursion in base-2 units, linear-space inner product with running offset c,
// renormalized by butterfly max every 4 steps.
__global__ __launch_bounds__(64) void crf_chains(
    const float* __restrict__ feats, const float* __restrict__ trans,
    const int* __restrict__ tags, const int* __restrict__ lengths,
    float* __restrict__ acc)
{
  const int b    = blockIdx.x;
  const int lane = threadIdx.x;
  const int half = lane >> 5;
  const int j    = lane & 31;
  const int je   = (j < NS) ? j : (NS - 1);
  const bool isB = (half != 0);
  const int len  = lengths[b];
  const int lenm1 = len - 1;

  const int fsteps = (len < MID) ? len : MID;
  const int bsteps = (len > MID) ? (len - MID) : 0;
  const int steps  = isB ? bsteps : fsteps;
  const int maxsteps = (fsteps > bsteps) ? fsteps : bsteps;

  // P fragments: fwd lane j holds row j of 2^(trans*L2E); bwd lane j holds column j.
  // Pad lanes (j>=24) get all-zero rows -> their y==0 -> rel=-inf, self-quarantined.
  float p[NS];
  #pragma unroll
  for (int jj = 0; jj < NS; ++jj) {
    int idx = isB ? (jj * NS + je) : (je * NS + jj);
    float tv = trans[idx];
    p[jj] = fexp2(((j < NS) ? tv : NEGBIG) * L2E);
  }

  float rel;
  {
    float relF = (j == KSTART) ? 0.0f : NEGBIG;
    float relB = trans[KSTOP * NS + je] * L2E;
    relB = (j < NS) ? relB : NEGBIG;
    rel = isB ? relB : relF;
  }
  float c = 0.0f;

  const float* fb = feats + (size_t)b * (TLEN * NS);

  // clamped feat loader: fwd t=k (<=1027, always in range), bwd t=len-1-k clamped at 0
  #define LDF(KK) ({ int t_ = isB ? (lenm1 - (KK)) : (KK); t_ = (t_ < 0) ? 0 : t_; fb[t_ * NS + je]; })

  float fc0 = LDF(0), fc1 = LDF(1), fc2 = LDF(2), fc3 = LDF(3);

  #define STEP(U, FC) { \
    const int kk = k0 + (U); \
    const float fl = (FC) * L2E; \
    const float gg = fexp2(rel + (isB ? fl : 0.0f)); \
    float y0 = 0.f, y1 = 0.f, y2 = 0.f, y3 = 0.f; \
    DOTALL(gg); \
    const float yy = (y0 + y1) + (y2 + y3); \
    float nrel = flog2(yy) + (isB ? 0.0f : fl); \
    rel = (kk < steps) ? nrel : rel; \
  }

  for (int k0 = 0; k0 < maxsteps; k0 += 4) {
    // prefetch next group's feats (distance 4..7 steps ahead of use)
    float fn0 = LDF(k0 + 4), fn1 = LDF(k0 + 5), fn2 = LDF(k0 + 6), fn3 = LDF(k0 + 7);
    STEP(0, fc0)
    STEP(1, fc1)
    STEP(2, fc2)
    STEP(3, fc3)
    // renorm: butterfly max within each 32-half, shift rel->c (invariant-preserving,
    // safe to apply to inactive lanes too)
    float mres = rel;
    mres = fmaxf(mres, SWZ(mres, 0x041F));
    mres = fmaxf(mres, SWZ(mres, 0x081F));
    mres = fmaxf(mres, SWZ(mres, 0x101F));
    mres = fmaxf(mres, SWZ(mres, 0x201F));
    mres = fmaxf(mres, SWZ(mres, 0x401F));
    rel -= mres;
    c += mres;
    fc0 = fn0; fc1 = fn1; fc2 = fn2; fc3 = fn3;
  }

  // combine: alpha2 = log2 sum_j 2^(fv2_M[j] + beta2_M[j]); halves exchange via LDS
  __shared__ float xch[64];
  float v = rel + c;
  xch[lane] = v;
  __syncthreads();
  float s2 = v + xch[lane ^ 32];

  float mm = s2;
  mm = fmaxf(mm, SWZ(mm, 0x041F));
  mm = fmaxf(mm, SWZ(mm, 0x081F));
  mm = fmaxf(mm, SWZ(mm, 0x101F));
  mm = fmaxf(mm, SWZ(mm, 0x201F));
  mm = fmaxf(mm, SWZ(mm, 0x401F));
  float pe = fexp2(s2 - mm);
  pe += SWZ(pe, 0x041F);
  pe += SWZ(pe, 0x081F);
  pe += SWZ(pe, 0x101F);
  pe += SWZ(pe, 0x201F);
  pe += SWZ(pe, 0x401F);
  float alpha2 = mm + flog2(pe);

  if (lane == 0) atomicAdd(acc, alpha2 * LN2F);   // convert base-2 -> nats
  #undef LDF
  #undef STEP
}

// gold score: per (b,t) gather, block-reduced, subtracted from the accumulator
__global__ __launch_bounds__(256) void crf_gold(
    const float* __restrict__ feats, const float* __restrict__ trans,
    const int* __restrict__ tags, const int* __restrict__ lengths,
    float* __restrict__ acc)
{
  const int b   = blockIdx.x;
  const int tid = threadIdx.x;
  const int len = lengths[b];
  const int* tg = tags + (size_t)b * TLEN;
  const float* fb = feats + (size_t)b * (TLEN * NS);

  float s = 0.0f;
  for (int t = tid; t < len; t += 256) {
    int cur  = tg[t];
    int prev = (t == 0) ? KSTART : tg[t - 1];
    s += trans[cur * NS + prev] + fb[t * NS + cur];
  }

  __shared__ float red[256];
  red[tid] = s;
  __syncthreads();
  for (int off = 128; off > 0; off >>= 1) {
    if (tid < off) red[tid] += red[tid + off];
    __syncthreads();
  }
  if (tid == 0) {
    float g = red[0] + trans[KSTOP * NS + tg[len - 1]];
    atomicAdd(acc, -g);
  }
}

__global__ void crf_final(float* out) {
  out[0] = out[0] * (1.0f / (float)NBATCH);
}

extern "C" void kernel_launch(void* const* d_in, const int* in_sizes, int n_in,
                              void* d_out, int out_size, void* d_ws, size_t ws_size,
                              hipStream_t stream) {
  const float* feats   = (const float*)d_in[0];
  const float* trans   = (const float*)d_in[1];
  const int*   tags    = (const int*)d_in[2];
  const int*   lengths = (const int*)d_in[3];
  float* out = (float*)d_out;

  hipMemsetAsync(out, 0, sizeof(float), stream);   // d_out is re-poisoned each call
  crf_chains<<<NBATCH, 64, 0, stream>>>(feats, trans, tags, lengths, out);
  crf_gold<<<NBATCH, 256, 0, stream>>>(feats, trans, tags, lengths, out);
  crf_final<<<1, 1, 0, stream>>>(out);
}

// Round 3
// 345.377 us; speedup vs baseline: 1.2082x; 1.2082x over previous
//
#include <hip/hip_runtime.h>
#include <math.h>

#define NBATCH 512
#define TLEN   2048
#define NS     24
#define KSTART 22
#define KSTOP  23
#define MID    1024
#define L2E    1.4426950408889634f
#define LN2F   0.6931471805599453f

__device__ __forceinline__ float fexp2(float x) {
#if __has_builtin(__builtin_amdgcn_exp2f)
  return __builtin_amdgcn_exp2f(x);
#else
  return exp2f(x);
#endif
}
__device__ __forceinline__ float flog2(float x) {
#if __has_builtin(__builtin_amdgcn_logf)
  return __builtin_amdgcn_logf(x);
#else
  return __log2f(x);
#endif
}

// wave-uniform broadcast of lane k's value through an SGPR (VALU latency, no LDS pipe)
__device__ __forceinline__ float rl(float v, int k) {
  return __int_as_float(__builtin_amdgcn_readlane(__float_as_int(v), k));
}

// 32-lane-group swizzle (used only in epilogue reductions, off the hot path)
#define SWZ(X, IMM) __int_as_float(__builtin_amdgcn_ds_swizzle(__float_as_int(X), (IMM)))

// Linear-space chain: g' = (P . g) * ef   (fwd)   or   g' = P^T . (g * ef)  (bwd)
// P rows/cols are exp2(trans*L2E) held per-lane; broadcast of the 24 state values
// goes through v_readlane -> SGPR -> v_fmac (one SGPR operand allowed per VALU op).
// Renorm every 4 steps: lane-0 exponent extracted via bit ops, all lanes scaled by
// 2^-E, E accumulated in an integer (exact).
template<bool ISB>
__device__ __forceinline__ void run_chain(
    const float* __restrict__ fb, const float* __restrict__ trans,
    int steps, int lenm1, int j, int je,
    float* __restrict__ outg, float* __restrict__ outc)
{
  const bool act = (j < NS);

  float p[NS];
  #pragma unroll
  for (int k = 0; k < NS; ++k) {
    int idx = ISB ? (k * NS + je) : (je * NS + k);
    float tv = trans[idx];
    p[k] = act ? fexp2(tv * L2E) : 0.0f;   // NEG rows/cols underflow to exact 0
  }

  float g;
  if (ISB) g = act ? fexp2(trans[KSTOP * NS + je] * L2E) : 0.0f;  // beta init = trans[STOP,:]
  else     g = (j == KSTART) ? 1.0f : 0.0f;                        // alpha init = delta(START)
  int cE = 0;

  auto ldf = [&](int k) -> float {
    int t = ISB ? (lenm1 - k) : k;
    t = (t < 0) ? 0 : t;                   // bwd prefetch clamp; fwd always in range
    return fb[t * NS + je];
  };

#define DOT24(SRC) \
  y0 = p[0]*rl(SRC,0);             y1 = p[1]*rl(SRC,1);             y2 = p[2]*rl(SRC,2);             y3 = p[3]*rl(SRC,3); \
  y0 = fmaf(p[4],  rl(SRC,4),  y0); y1 = fmaf(p[5],  rl(SRC,5),  y1); y2 = fmaf(p[6],  rl(SRC,6),  y2); y3 = fmaf(p[7],  rl(SRC,7),  y3); \
  y0 = fmaf(p[8],  rl(SRC,8),  y0); y1 = fmaf(p[9],  rl(SRC,9),  y1); y2 = fmaf(p[10], rl(SRC,10), y2); y3 = fmaf(p[11], rl(SRC,11), y3); \
  y0 = fmaf(p[12], rl(SRC,12), y0); y1 = fmaf(p[13], rl(SRC,13), y1); y2 = fmaf(p[14], rl(SRC,14), y2); y3 = fmaf(p[15], rl(SRC,15), y3); \
  y0 = fmaf(p[16], rl(SRC,16), y0); y1 = fmaf(p[17], rl(SRC,17), y1); y2 = fmaf(p[18], rl(SRC,18), y2); y3 = fmaf(p[19], rl(SRC,19), y3); \
  y0 = fmaf(p[20], rl(SRC,20), y0); y1 = fmaf(p[21], rl(SRC,21), y1); y2 = fmaf(p[22], rl(SRC,22), y2); y3 = fmaf(p[23], rl(SRC,23), y3);

#define STEP1(EU) { float y0, y1, y2, y3; \
    if constexpr (ISB) { float m = g * (EU); DOT24(m); g = (y0 + y1) + (y2 + y3); } \
    else               { DOT24(g); g = ((y0 + y1) + (y2 + y3)) * (EU); } }

#define RENORM { int b0_ = __builtin_amdgcn_readlane(__float_as_int(g), 0); \
    int er_ = (b0_ >> 23) & 0xFF; int E_ = (er_ == 0) ? 0 : (er_ - 127); \
    cE += E_; g *= __int_as_float((127 - E_) << 23); }

  // software pipeline: e0..e7 = 2^ factors for current group (ready);
  // f0..f7 = raw feats for next group; loads issued 8-16 steps ahead of use.
  float f0 = ldf(0), f1 = ldf(1), f2 = ldf(2), f3 = ldf(3),
        f4 = ldf(4), f5 = ldf(5), f6 = ldf(6), f7 = ldf(7);
  float e0 = fexp2(f0 * L2E), e1 = fexp2(f1 * L2E), e2 = fexp2(f2 * L2E), e3 = fexp2(f3 * L2E),
        e4 = fexp2(f4 * L2E), e5 = fexp2(f5 * L2E), e6 = fexp2(f6 * L2E), e7 = fexp2(f7 * L2E);
  f0 = ldf(8);  f1 = ldf(9);  f2 = ldf(10); f3 = ldf(11);
  f4 = ldf(12); f5 = ldf(13); f6 = ldf(14); f7 = ldf(15);

  int k0 = 0;
  for (; k0 + 8 <= steps; k0 += 8) {
    float n0 = ldf(k0 + 16), n1 = ldf(k0 + 17), n2 = ldf(k0 + 18), n3 = ldf(k0 + 19),
          n4 = ldf(k0 + 20), n5 = ldf(k0 + 21), n6 = ldf(k0 + 22), n7 = ldf(k0 + 23);
    float x0 = fexp2(f0 * L2E), x1 = fexp2(f1 * L2E), x2 = fexp2(f2 * L2E), x3 = fexp2(f3 * L2E),
          x4 = fexp2(f4 * L2E), x5 = fexp2(f5 * L2E), x6 = fexp2(f6 * L2E), x7 = fexp2(f7 * L2E);
    STEP1(e0) STEP1(e1) STEP1(e2) STEP1(e3)
    RENORM
    STEP1(e4) STEP1(e5) STEP1(e6) STEP1(e7)
    RENORM
    f0 = n0; f1 = n1; f2 = n2; f3 = n3; f4 = n4; f5 = n5; f6 = n6; f7 = n7;
    e0 = x0; e1 = x1; e2 = x2; e3 = x3; e4 = x4; e5 = x5; e6 = x6; e7 = x7;
  }
  int r = steps - k0;
  if (r > 0) STEP1(e0)
  if (r > 1) STEP1(e1)
  if (r > 2) STEP1(e2)
  if (r > 3) STEP1(e3)
  if (r > 4) { RENORM STEP1(e4) }
  if (r > 5) STEP1(e5)
  if (r > 6) STEP1(e6)
  RENORM   // final: lane-0 exponent == 0, all |log2 g| <= ~15 -> products fp32-safe

  if (act) outg[j] = g;
  if (j == 0) *outc = (float)cE;

#undef DOT24
#undef STEP1
#undef RENORM
}

// one block per batch: wave 0 = forward chain, wave 1 = backward chain; combine in-block.
__global__ __launch_bounds__(128) void crf_chains(
    const float* __restrict__ feats, const float* __restrict__ trans,
    const int* __restrict__ lengths, float* __restrict__ acc)
{
  __shared__ float shg[2][NS];
  __shared__ float shc[2];
  const int b   = blockIdx.x;
  const int tid = threadIdx.x;
  const int dir = tid >> 6;          // wave-uniform
  const int j   = tid & 63;
  const int je  = (j < NS) ? j : (NS - 1);
  const int len = lengths[b];
  const int lenm1 = len - 1;
  const float* fb = feats + (size_t)b * (TLEN * NS);

  if (dir == 0) {
    int fsteps = (len < MID) ? len : MID;
    run_chain<false>(fb, trans, fsteps, lenm1, j, je, shg[0], &shc[0]);
  } else {
    int bsteps = (len > MID) ? (len - MID) : 0;
    run_chain<true>(fb, trans, bsteps, lenm1, j, je, shg[1], &shc[1]);
  }
  __syncthreads();

  if (tid < 32) {
    float prod = (tid < NS) ? shg[0][tid] * shg[1][tid] : 0.0f;
    prod += SWZ(prod, 0x041F);
    prod += SWZ(prod, 0x081F);
    prod += SWZ(prod, 0x101F);
    prod += SWZ(prod, 0x201F);
    prod += SWZ(prod, 0x401F);
    if (tid == 0) {
      float alpha2 = shc[0] + shc[1] + flog2(prod);
      atomicAdd(acc, alpha2 * LN2F);
    }
  }
}

// gold score: coalesced tags, scattered (L3-resident) feat gather, wave-level reduce
__global__ __launch_bounds__(256) void crf_gold(
    const float* __restrict__ feats, const float* __restrict__ trans,
    const int* __restrict__ tags, const int* __restrict__ lengths,
    float* __restrict__ acc)
{
  const int b   = blockIdx.x;
  const int tid = threadIdx.x;
  const int len = lengths[b];
  const int* tg = tags + (size_t)b * TLEN;
  const float* fb = feats + (size_t)b * (TLEN * NS);

  float s = 0.0f;
  for (int t = tid; t < len; t += 256) {
    int cur  = tg[t];
    int prev = (t == 0) ? KSTART : tg[t - 1];
    s += trans[cur * NS + prev] + fb[t * NS + cur];
  }
  if (tid == 0) s += trans[KSTOP * NS + tg[len - 1]];
  s = -s;
  s += SWZ(s, 0x041F);
  s += SWZ(s, 0x081F);
  s += SWZ(s, 0x101F);
  s += SWZ(s, 0x201F);
  s += SWZ(s, 0x401F);
  if ((tid & 31) == 0) atomicAdd(acc, s);
}

__global__ void crf_final(float* out) {
  out[0] = out[0] * (1.0f / (float)NBATCH);
}

extern "C" void kernel_launch(void* const* d_in, const int* in_sizes, int n_in,
                              void* d_out, int out_size, void* d_ws, size_t ws_size,
                              hipStream_t stream) {
  const float* feats   = (const float*)d_in[0];
  const float* trans   = (const float*)d_in[1];
  const int*   tags    = (const int*)d_in[2];
  const int*   lengths = (const int*)d_in[3];
  float* out = (float*)d_out;

  hipMemsetAsync(out, 0, sizeof(float), stream);
  crf_chains<<<NBATCH, 128, 0, stream>>>(feats, trans, lengths, out);
  crf_gold<<<NBATCH, 256, 0, stream>>>(feats, trans, tags, lengths, out);
  crf_final<<<1, 1, 0, stream>>>(out);
}

// Round 4
// 331.622 us; speedup vs baseline: 1.2584x; 1.0415x over previous
//
#include <hip/hip_runtime.h>
#include <math.h>

#define NBATCH 512
#define TLEN   2048
#define NS     24
#define KSTART 22
#define KSTOP  23
#define MID    1024
#define L2E    1.4426950408889634f
#define LN2F   0.6931471805599453f

#define GOLD_CHUNKS 4
#define GOLD_CLEN   (TLEN / GOLD_CHUNKS)          // 512
#define WS_TOTAL    (NBATCH + NBATCH * GOLD_CHUNKS)  // 2560 floats

__device__ __forceinline__ float fexp2(float x) {
#if __has_builtin(__builtin_amdgcn_exp2f)
  return __builtin_amdgcn_exp2f(x);
#else
  return exp2f(x);
#endif
}
__device__ __forceinline__ float flog2(float x) {
#if __has_builtin(__builtin_amdgcn_logf)
  return __builtin_amdgcn_logf(x);
#else
  return __log2f(x);
#endif
}

// wave-uniform broadcast of lane k's value through an SGPR
__device__ __forceinline__ float rl(float v, int k) {
  return __int_as_float(__builtin_amdgcn_readlane(__float_as_int(v), k));
}

#define SWZ(X, IMM) __int_as_float(__builtin_amdgcn_ds_swizzle(__float_as_int(X), (IMM)))

// Linear-space chain: g' = (P . g) * ef  (fwd)  or  g' = P^T . (g * ef)  (bwd).
// All 24 readlanes are grouped BEFORE the fmac block (separation kills any
// SGPR-write -> VALU-read pairing hazard and gives the scheduler slack).
template<bool ISB>
__device__ __forceinline__ void run_chain(
    const float* __restrict__ fb, const float* __restrict__ trans,
    int steps, int lenm1, int j, int je,
    float* __restrict__ outg, float* __restrict__ outc)
{
  const bool act = (j < NS);

  float p[NS];
  #pragma unroll
  for (int k = 0; k < NS; ++k) {
    int idx = ISB ? (k * NS + je) : (je * NS + k);
    float tv = trans[idx];
    p[k] = act ? fexp2(tv * L2E) : 0.0f;   // NEG rows/cols underflow to exact 0
  }

  float g;
  if (ISB) g = act ? fexp2(trans[KSTOP * NS + je] * L2E) : 0.0f;
  else     g = (j == KSTART) ? 1.0f : 0.0f;
  int cE = 0;

  auto ldf = [&](int k) -> float {
    int t = ISB ? (lenm1 - k) : k;
    t = (t < 0) ? 0 : t;
    return fb[t * NS + je];
  };

#define DOT24(SRC) \
  const float s0  = rl(SRC, 0),  s1  = rl(SRC, 1),  s2  = rl(SRC, 2),  s3  = rl(SRC, 3),  \
              s4  = rl(SRC, 4),  s5  = rl(SRC, 5),  s6  = rl(SRC, 6),  s7  = rl(SRC, 7),  \
              s8  = rl(SRC, 8),  s9  = rl(SRC, 9),  s10 = rl(SRC, 10), s11 = rl(SRC, 11), \
              s12 = rl(SRC, 12), s13 = rl(SRC, 13), s14 = rl(SRC, 14), s15 = rl(SRC, 15), \
              s16 = rl(SRC, 16), s17 = rl(SRC, 17), s18 = rl(SRC, 18), s19 = rl(SRC, 19), \
              s20 = rl(SRC, 20), s21 = rl(SRC, 21), s22 = rl(SRC, 22), s23 = rl(SRC, 23); \
  y0 = p[0] * s0;              y1 = p[1] * s1;              y2 = p[2] * s2;              y3 = p[3] * s3; \
  y0 = fmaf(p[4],  s4,  y0);   y1 = fmaf(p[5],  s5,  y1);   y2 = fmaf(p[6],  s6,  y2);   y3 = fmaf(p[7],  s7,  y3); \
  y0 = fmaf(p[8],  s8,  y0);   y1 = fmaf(p[9],  s9,  y1);   y2 = fmaf(p[10], s10, y2);   y3 = fmaf(p[11], s11, y3); \
  y0 = fmaf(p[12], s12, y0);   y1 = fmaf(p[13], s13, y1);   y2 = fmaf(p[14], s14, y2);   y3 = fmaf(p[15], s15, y3); \
  y0 = fmaf(p[16], s16, y0);   y1 = fmaf(p[17], s17, y1);   y2 = fmaf(p[18], s18, y2);   y3 = fmaf(p[19], s19, y3); \
  y0 = fmaf(p[20], s20, y0);   y1 = fmaf(p[21], s21, y1);   y2 = fmaf(p[22], s22, y2);   y3 = fmaf(p[23], s23, y3);

#define STEP1(EU) { float y0, y1, y2, y3; \
    if constexpr (ISB) { float m = g * (EU); DOT24(m); g = (y0 + y1) + (y2 + y3); } \
    else               { DOT24(g); g = ((y0 + y1) + (y2 + y3)) * (EU); } }

#define RENORM { int b0_ = __builtin_amdgcn_readlane(__float_as_int(g), 0); \
    int er_ = (b0_ >> 23) & 0xFF; int E_ = (er_ == 0) ? 0 : (er_ - 127); \
    cE += E_; g *= __int_as_float((127 - E_) << 23); }

  float f0 = ldf(0), f1 = ldf(1), f2 = ldf(2), f3 = ldf(3),
        f4 = ldf(4), f5 = ldf(5), f6 = ldf(6), f7 = ldf(7);
  float e0 = fexp2(f0 * L2E), e1 = fexp2(f1 * L2E), e2 = fexp2(f2 * L2E), e3 = fexp2(f3 * L2E),
        e4 = fexp2(f4 * L2E), e5 = fexp2(f5 * L2E), e6 = fexp2(f6 * L2E), e7 = fexp2(f7 * L2E);
  f0 = ldf(8);  f1 = ldf(9);  f2 = ldf(10); f3 = ldf(11);
  f4 = ldf(12); f5 = ldf(13); f6 = ldf(14); f7 = ldf(15);

  int k0 = 0;
  for (; k0 + 8 <= steps; k0 += 8) {
    float n0 = ldf(k0 + 16), n1 = ldf(k0 + 17), n2 = ldf(k0 + 18), n3 = ldf(k0 + 19),
          n4 = ldf(k0 + 20), n5 = ldf(k0 + 21), n6 = ldf(k0 + 22), n7 = ldf(k0 + 23);
    float x0 = fexp2(f0 * L2E), x1 = fexp2(f1 * L2E), x2 = fexp2(f2 * L2E), x3 = fexp2(f3 * L2E),
          x4 = fexp2(f4 * L2E), x5 = fexp2(f5 * L2E), x6 = fexp2(f6 * L2E), x7 = fexp2(f7 * L2E);
    STEP1(e0) STEP1(e1) STEP1(e2) STEP1(e3)
    RENORM
    STEP1(e4) STEP1(e5) STEP1(e6) STEP1(e7)
    RENORM
    f0 = n0; f1 = n1; f2 = n2; f3 = n3; f4 = n4; f5 = n5; f6 = n6; f7 = n7;
    e0 = x0; e1 = x1; e2 = x2; e3 = x3; e4 = x4; e5 = x5; e6 = x6; e7 = x7;
  }
  int r = steps - k0;
  if (r > 0) STEP1(e0)
  if (r > 1) STEP1(e1)
  if (r > 2) STEP1(e2)
  if (r > 3) STEP1(e3)
  if (r > 4) { RENORM STEP1(e4) }
  if (r > 5) STEP1(e5)
  if (r > 6) STEP1(e6)
  RENORM

  if (act) outg[j] = g;
  if (j == 0) *outc = (float)cE;

#undef DOT24
#undef STEP1
#undef RENORM
}

// one block per batch: wave 0 = forward, wave 1 = backward; combine in-block,
// write per-batch alpha (nats) to ws[b]. NO atomics.
__global__ __launch_bounds__(128) __attribute__((amdgpu_waves_per_eu(1, 2)))
void crf_chains(
    const float* __restrict__ feats, const float* __restrict__ trans,
    const int* __restrict__ lengths, float* __restrict__ ws)
{
  __shared__ float shg[2][NS];
  __shared__ float shc[2];
  const int b   = blockIdx.x;
  const int tid = threadIdx.x;
  const int dir = tid >> 6;
  const int j   = tid & 63;
  const int je  = (j < NS) ? j : (NS - 1);
  const int len = lengths[b];
  const int lenm1 = len - 1;
  const float* fb = feats + (size_t)b * (TLEN * NS);

  if (dir == 0) {
    int fsteps = (len < MID) ? len : MID;
    run_chain<false>(fb, trans, fsteps, lenm1, j, je, shg[0], &shc[0]);
  } else {
    int bsteps = (len > MID) ? (len - MID) : 0;
    run_chain<true>(fb, trans, bsteps, lenm1, j, je, shg[1], &shc[1]);
  }
  __syncthreads();

  if (tid < 32) {
    float prod = (tid < NS) ? shg[0][tid] * shg[1][tid] : 0.0f;
    prod += SWZ(prod, 0x041F);
    prod += SWZ(prod, 0x081F);
    prod += SWZ(prod, 0x101F);
    prod += SWZ(prod, 0x201F);
    prod += SWZ(prod, 0x401F);
    if (tid == 0) {
      float alpha2 = shc[0] + shc[1] + flog2(prod);
      ws[b] = alpha2 * LN2F;
    }
  }
}

// gold score: 4 chunk-blocks per batch (512 t each, 2 t/thread), LDS tree
// reduce, ONE plain store per block into ws[NBATCH + blk]. NO atomics.
__global__ __launch_bounds__(256) void crf_gold(
    const float* __restrict__ feats, const float* __restrict__ trans,
    const int* __restrict__ tags, const int* __restrict__ lengths,
    float* __restrict__ ws)
{
  const int blk = blockIdx.x;
  const int b   = blk >> 2;           // batch
  const int c   = blk & 3;            // chunk
  const int tid = threadIdx.x;
  const int len = lengths[b];
  const int* tg = tags + (size_t)b * TLEN;
  const float* fb = feats + (size_t)b * (TLEN * NS);

  const int t0 = c * GOLD_CLEN + tid;
  const int t1 = t0 + 256;

  float s = 0.0f;
  if (t0 < len) {
    int cur  = tg[t0];
    int prev = (t0 == 0) ? KSTART : tg[t0 - 1];
    s += trans[cur * NS + prev] + fb[t0 * NS + cur];
  }
  if (t1 < len) {
    int cur  = tg[t1];
    int prev = tg[t1 - 1];
    s += trans[cur * NS + prev] + fb[t1 * NS + cur];
  }
  if (c == 0 && tid == 0) s += trans[KSTOP * NS + tg[len - 1]];  // STOP term once

  __shared__ float red[256];
  red[tid] = s;
  __syncthreads();
  for (int off = 128; off > 0; off >>= 1) {
    if (tid < off) red[tid] += red[tid + off];
    __syncthreads();
  }
  if (tid == 0) ws[NBATCH + blk] = -red[0];   // negative: gold is subtracted
}

// reduce all 2560 partials -> mean
__global__ __launch_bounds__(256) void crf_final(const float* __restrict__ ws,
                                                 float* __restrict__ out)
{
  const int tid = threadIdx.x;
  float s = 0.0f;
  for (int i = tid; i < WS_TOTAL; i += 256) s += ws[i];
  __shared__ float red[256];
  red[tid] = s;
  __syncthreads();
  for (int off = 128; off > 0; off >>= 1) {
    if (tid < off) red[tid] += red[tid + off];
    __syncthreads();
  }
  if (tid == 0) out[0] = red[0] * (1.0f / (float)NBATCH);
}

extern "C" void kernel_launch(void* const* d_in, const int* in_sizes, int n_in,
                              void* d_out, int out_size, void* d_ws, size_t ws_size,
                              hipStream_t stream) {
  const float* feats   = (const float*)d_in[0];
  const float* trans   = (const float*)d_in[1];
  const int*   tags    = (const int*)d_in[2];
  const int*   lengths = (const int*)d_in[3];
  float* out = (float*)d_out;
  float* ws  = (float*)d_ws;

  crf_chains<<<NBATCH, 128, 0, stream>>>(feats, trans, lengths, ws);
  crf_gold<<<NBATCH * GOLD_CHUNKS, 256, 0, stream>>>(feats, trans, tags, lengths, ws);
  crf_final<<<1, 256, 0, stream>>>(ws, out);
}